// Round 5
// baseline (222.456 us; speedup 1.0000x reference)
//
#include <hip/hip_runtime.h>
#include <hip/hip_bf16.h>
#include <math.h>

#define D_DIM 128
#define FF_DIM 512

typedef __attribute__((ext_vector_type(8))) short bf16x8;
typedef __attribute__((ext_vector_type(4))) float f32x4;
typedef __attribute__((ext_vector_type(4))) unsigned short u16x4;
typedef __attribute__((ext_vector_type(2))) unsigned u32x2;

__device__ __forceinline__ short f2bf(float f) {
    union { float f; unsigned u; } x; x.f = f;
    unsigned r = x.u + 0x7FFF + ((x.u >> 16) & 1);
    return (short)(r >> 16);
}
__device__ __forceinline__ float bf2f(short s) {
    union { unsigned u; float f; } x;
    x.u = ((unsigned)(unsigned short)s) << 16;
    return x.f;
}

__device__ __forceinline__ void load_lds16(const short* g, short* l) {
    __builtin_amdgcn_global_load_lds(
        (const __attribute__((address_space(1))) unsigned int*)g,
        (__attribute__((address_space(3))) unsigned int*)l, 16, 0, 0);
}

// ---------------------------------------------------------------------------
// bf16 MFMA GEMM: C[MP,Nc] = A[MP,K] @ W[Nc,K]^T + bias (+relu) (f32/bf16 C)
// 128x128 tile, BK=32, 256 threads (4 waves, 2x2), 4x4 16x16 frags per wave.
// KVPACK: remap output cols so K/V dims interleave as {k0,k1,v0,v1} per pair.
// ---------------------------------------------------------------------------
template<int OUT_BF16, int RELU, int KVPACK>
__global__ __launch_bounds__(256) void gemm_mfma(
    const short* __restrict__ A, const short* __restrict__ B,
    const float* __restrict__ bias, void* __restrict__ C,
    int Nc, int K)
{
    __shared__ short lA[128 * 32];
    __shared__ short lB[128 * 32];

    const int tid  = threadIdx.x;
    const int lane = tid & 63;
    const int wave = tid >> 6;
    const int wr = wave >> 1, wc = wave & 1;
    const int row0 = blockIdx.y * 128;
    const int col0 = blockIdx.x * 128;
    const int fr = lane & 15;
    const int fq = lane >> 4;
    const int sw = (fr >> 1) & 3;
    const int rdoff = (fq ^ sw) * 8;

    f32x4 acc[4][4] = {};

    for (int k0 = 0; k0 < K; k0 += 32) {
        __syncthreads();
#pragma unroll
        for (int i = 0; i < 2; ++i) {
            int c  = i * 256 + tid;
            int r  = c >> 2;
            int qs = c & 3;
            int qg = qs ^ ((r >> 1) & 3);
            load_lds16(A + (size_t)(row0 + r) * K + k0 + qg * 8, lA + c * 8);
            load_lds16(B + (size_t)(col0 + r) * K + k0 + qg * 8, lB + c * 8);
        }
        __syncthreads();

        bf16x8 af[4], bfr[4];
#pragma unroll
        for (int m = 0; m < 4; ++m)
            af[m] = *(const bf16x8*)&lA[(wr * 64 + m * 16 + fr) * 32 + rdoff];
#pragma unroll
        for (int n2 = 0; n2 < 4; ++n2)
            bfr[n2] = *(const bf16x8*)&lB[(wc * 64 + n2 * 16 + fr) * 32 + rdoff];
#pragma unroll
        for (int m = 0; m < 4; ++m)
#pragma unroll
            for (int n2 = 0; n2 < 4; ++n2)
                acc[m][n2] = __builtin_amdgcn_mfma_f32_16x16x32_bf16(
                    af[m], bfr[n2], acc[m][n2], 0, 0, 0);
    }

#pragma unroll
    for (int m = 0; m < 4; ++m) {
        int r = row0 + wr * 64 + m * 16 + fq * 4;
#pragma unroll
        for (int n2 = 0; n2 < 4; ++n2) {
            int c = col0 + wc * 64 + n2 * 16 + fr;
            float bb = bias[c];
            int cc = c;
            if (KVPACK) {
                if (c >= 256)      { int d = c - 256; cc = 128 + ((d >> 1) << 2) + 2 + (d & 1); }
                else if (c >= 128) { int d = c - 128; cc = 128 + ((d >> 1) << 2) + (d & 1); }
            }
#pragma unroll
            for (int j = 0; j < 4; ++j) {
                float v = acc[m][n2][j] + bb;
                if (RELU) v = fmaxf(v, 0.0f);
                if (OUT_BF16)
                    ((short*)C)[(size_t)(r + j) * Nc + cc] = f2bf(v);
                else
                    ((float*)C)[(size_t)(r + j) * Nc + cc] = v;
            }
        }
    }
}

// ---------------------------------------------------------------------------
// Fused GEMM (Nc=128, 128x128 tile) + residual + LayerNorm epilogue.
// LN stats via fr-group shfl reduce + 3KB LDS cross-wave combine.
// WRITE_BF=1: write out32 (rows<n) AND outbf (all rows); else out32 rows<n.
// ---------------------------------------------------------------------------
template<int KD, int WRITE_BF>
__global__ __launch_bounds__(256) void gemm_ln(
    const short* __restrict__ A, const short* __restrict__ B,
    const float* __restrict__ bias, const float* __restrict__ res,
    const float* __restrict__ gamma, const float* __restrict__ beta,
    float* __restrict__ out32, short* __restrict__ outbf, int n)
{
    __shared__ short lA[128 * 32];
    __shared__ short lB[128 * 32];
    __shared__ float sums[128][2], sqs[128][2];
    __shared__ float muA[128], rsA[128];

    const int tid  = threadIdx.x;
    const int lane = tid & 63;
    const int wave = tid >> 6;
    const int wr = wave >> 1, wc = wave & 1;
    const int row0 = blockIdx.x * 128;
    const int fr = lane & 15;
    const int fq = lane >> 4;
    const int sw = (fr >> 1) & 3;
    const int rdoff = (fq ^ sw) * 8;

    f32x4 acc[4][4] = {};

    for (int k0 = 0; k0 < KD; k0 += 32) {
        __syncthreads();
#pragma unroll
        for (int i = 0; i < 2; ++i) {
            int c  = i * 256 + tid;
            int r  = c >> 2;
            int qs = c & 3;
            int qg = qs ^ ((r >> 1) & 3);
            load_lds16(A + (size_t)(row0 + r) * KD + k0 + qg * 8, lA + c * 8);
            load_lds16(B + (size_t)r * KD + k0 + qg * 8, lB + c * 8);
        }
        __syncthreads();

        bf16x8 af[4], bfr[4];
#pragma unroll
        for (int m = 0; m < 4; ++m)
            af[m] = *(const bf16x8*)&lA[(wr * 64 + m * 16 + fr) * 32 + rdoff];
#pragma unroll
        for (int n2 = 0; n2 < 4; ++n2)
            bfr[n2] = *(const bf16x8*)&lB[(wc * 64 + n2 * 16 + fr) * 32 + rdoff];
#pragma unroll
        for (int m = 0; m < 4; ++m)
#pragma unroll
            for (int n2 = 0; n2 < 4; ++n2)
                acc[m][n2] = __builtin_amdgcn_mfma_f32_16x16x32_bf16(
                    af[m], bfr[n2], acc[m][n2], 0, 0, 0);
    }

    // per-lane column constants
    float bicol[4], gcol[4], bcol[4];
#pragma unroll
    for (int n2 = 0; n2 < 4; ++n2) {
        int c = wc * 64 + n2 * 16 + fr;
        bicol[n2] = bias[c]; gcol[n2] = gamma[c]; bcol[n2] = beta[c];
    }

    // bias + residual, accumulate row partial sums, reduce across fr-group
#pragma unroll
    for (int m = 0; m < 4; ++m) {
#pragma unroll
        for (int j = 0; j < 4; ++j) {
            int rl = wr * 64 + m * 16 + fq * 4 + j;
            int rg = row0 + rl;
            float ps = 0.0f, pq = 0.0f;
#pragma unroll
            for (int n2 = 0; n2 < 4; ++n2) {
                float v = acc[m][n2][j] + bicol[n2];
                if (rg < n) v += res[(size_t)rg * 128 + wc * 64 + n2 * 16 + fr];
                acc[m][n2][j] = v;
                ps += v; pq += v * v;
            }
            ps += __shfl_xor(ps, 1); ps += __shfl_xor(ps, 2);
            ps += __shfl_xor(ps, 4); ps += __shfl_xor(ps, 8);
            pq += __shfl_xor(pq, 1); pq += __shfl_xor(pq, 2);
            pq += __shfl_xor(pq, 4); pq += __shfl_xor(pq, 8);
            if (fr == 0) { sums[rl][wc] = ps; sqs[rl][wc] = pq; }
        }
    }
    __syncthreads();
    if (tid < 128) {
        float s = sums[tid][0] + sums[tid][1];
        float q = sqs[tid][0] + sqs[tid][1];
        float mu = s * (1.0f / 128.0f);
        float var = q * (1.0f / 128.0f) - mu * mu;
        muA[tid] = mu;
        rsA[tid] = rsqrtf(var + 1e-5f);
    }
    __syncthreads();

#pragma unroll
    for (int m = 0; m < 4; ++m) {
#pragma unroll
        for (int j = 0; j < 4; ++j) {
            int rl = wr * 64 + m * 16 + fq * 4 + j;
            int rg = row0 + rl;
            float mu = muA[rl], rs = rsA[rl];
#pragma unroll
            for (int n2 = 0; n2 < 4; ++n2) {
                int c = wc * 64 + n2 * 16 + fr;
                float o = gcol[n2] * (acc[m][n2][j] - mu) * rs + bcol[n2];
                if (WRITE_BF) {
                    if (rg < n) out32[(size_t)rg * 128 + c] = o;
                    outbf[(size_t)rg * 128 + c] = (rg < n) ? f2bf(o) : (short)0;
                } else {
                    if (rg < n) out32[(size_t)rg * 128 + c] = o;
                }
            }
        }
    }
}

// ---------------------------------------------------------------------------
// prep: ns f32->bf16 (+ old copy, pad zero), weights ->bf16, zero counts/gcur
// ---------------------------------------------------------------------------
__global__ __launch_bounds__(256) void prep_kernel(
    const float* __restrict__ ns, short* __restrict__ nsbf,
    float* __restrict__ out_old, int n_elems, int mp_elems,
    const float* w0, const float* w1, const float* w2, const float* w3,
    short* o0, short* o1, short* o2, short* o3,
    int c0, int c1, int c2, int c3,
    int* __restrict__ counts, int nc1)
{
    int i = blockIdx.x * 256 + threadIdx.x;
    int i4 = i * 4;
    if (i4 < mp_elems) {
        if (i4 < n_elems) {
            float4 v = *(const float4*)(ns + i4);
            *(float4*)(out_old + i4) = v;
            u16x4 b;
            b.x = (unsigned short)f2bf(v.x); b.y = (unsigned short)f2bf(v.y);
            b.z = (unsigned short)f2bf(v.z); b.w = (unsigned short)f2bf(v.w);
            *(u16x4*)(nsbf + i4) = b;
        } else {
            u16x4 z = {0, 0, 0, 0};
            *(u16x4*)(nsbf + i4) = z;
        }
    }
    if (i < c0) o0[i] = f2bf(w0[i]);
    if (i < c1) o1[i] = f2bf(w1[i]);
    if (i < c2) o2[i] = f2bf(w2[i]);
    if (i < c3) o3[i] = f2bf(w3[i]);
    if (i < nc1) counts[i] = 0;
}

// ---------------------------------------------------------------------------
// CSR build: count -> atomic base alloc -> scatter (bucket order arbitrary)
// ---------------------------------------------------------------------------
__global__ __launch_bounds__(256) void count_kernel(
    const int* __restrict__ tgt, int* __restrict__ counts, int m)
{
    int i = blockIdx.x * blockDim.x + threadIdx.x;
    if (i < m) atomicAdd(&counts[tgt[i]], 1);
}

__global__ __launch_bounds__(256) void alloc_kernel(
    int* __restrict__ counts, int* __restrict__ offs,
    int* __restrict__ cursor, int n)
{
    int i = blockIdx.x * 256 + threadIdx.x;
    if (i < n) {
        int c = counts[i];
        int base = atomicAdd(&counts[n], c);   // counts[n] = global cursor
        offs[i] = base;
        cursor[i] = base;
    }
}

__global__ __launch_bounds__(256) void scatter_kernel(
    const int* __restrict__ src, const int* __restrict__ tgt,
    int* __restrict__ cursor, int* __restrict__ csr_src, int m)
{
    int i = blockIdx.x * blockDim.x + threadIdx.x;
    if (i < m) {
        int pos = atomicAdd(&cursor[tgt[i]], 1);
        csr_src[pos] = src[i];
    }
}

// ---------------------------------------------------------------------------
// Per-target-node attention: depth-4 pipeline + 4-edge-group softmax (exp2).
// One wave per node; lane covers dims {2l,2l+1}; 8-lane groups = heads.
// qkv layout: q[128] | kv-interleaved {k0,k1,v0,v1}*64 per row.
// ---------------------------------------------------------------------------
__global__ __launch_bounds__(256) void attn_kernel(
    const short* __restrict__ qkv, const int* __restrict__ offsets,
    const int* __restrict__ counts, const int* __restrict__ csr_src,
    short* __restrict__ agg, int n, int mp)
{
    int node = blockIdx.x * 4 + (threadIdx.x >> 6);
    int lane = threadIdx.x & 63;
    if (node >= mp) return;
    const int d0 = lane * 2;
    unsigned* outp = (unsigned*)(agg + (size_t)node * 128 + d0);
    if (node >= n) { *outp = 0u; return; }

    const float SC = 0.25f * 1.44269504088896340736f;  // fold scale+log2e
    unsigned qw = *(const unsigned*)(qkv + (size_t)node * 384 + d0);
    float q0 = bf2f((short)(qw & 0xFFFF)) * SC;
    float q1 = bf2f((short)(qw >> 16)) * SC;

    int beg = offsets[node];
    int end = beg + counts[node];

    float m = -INFINITY, l = 0.0f, acc0 = 0.0f, acc1 = 0.0f;
    const int kvoff = 128 + 4 * lane;

#define LOADKV(dst, IDX) { int s_ = __shfl(mysrc, (IDX) & 63); \
    dst = *(const u32x2*)(qkv + (size_t)s_ * 384 + kvoff); }

    for (int c0 = beg; c0 < end; c0 += 64) {
        int cnt = end - c0; if (cnt > 64) cnt = 64;
        int mysrc = (lane < cnt) ? csr_src[c0 + lane] : 0;

        u32x2 kv0, kv1, kv2, kv3;
        LOADKV(kv0, 0) LOADKV(kv1, 1) LOADKV(kv2, 2) LOADKV(kv3, 3)

        for (int g = 0; g < cnt; g += 4) {
            float s0, s1, s2, s3;
            unsigned w0, w1, w2, w3;
#define SCORE(J, KV, SJ, WJ) { u32x2 cur = KV; LOADKV(KV, g + 4 + J) \
            float part = q0 * bf2f((short)(cur.x & 0xFFFF)) \
                       + q1 * bf2f((short)(cur.x >> 16)); \
            part += __shfl_xor(part, 1); \
            part += __shfl_xor(part, 2); \
            part += __shfl_xor(part, 4); \
            SJ = (g + (J) < cnt) ? part : -INFINITY; \
            WJ = cur.y; }
            SCORE(0, kv0, s0, w0) SCORE(1, kv1, s1, w1)
            SCORE(2, kv2, s2, w2) SCORE(3, kv3, s3, w3)
#undef SCORE
            float mnew = fmaxf(fmaxf(fmaxf(s0, s1), fmaxf(s2, s3)), m);
            float corr = exp2f(m - mnew);
            float p0 = exp2f(s0 - mnew), p1 = exp2f(s1 - mnew);
            float p2 = exp2f(s2 - mnew), p3 = exp2f(s3 - mnew);
            l = l * corr + ((p0 + p1) + (p2 + p3));
            acc0 = acc0 * corr +
                ((p0 * bf2f((short)(w0 & 0xFFFF)) + p1 * bf2f((short)(w1 & 0xFFFF))) +
                 (p2 * bf2f((short)(w2 & 0xFFFF)) + p3 * bf2f((short)(w3 & 0xFFFF))));
            acc1 = acc1 * corr +
                ((p0 * bf2f((short)(w0 >> 16)) + p1 * bf2f((short)(w1 >> 16))) +
                 (p2 * bf2f((short)(w2 >> 16)) + p3 * bf2f((short)(w3 >> 16))));
            m = mnew;
        }
    }
#undef LOADKV

    float inv = (l > 0.0f) ? 1.0f / l : 0.0f;
    *outp = ((unsigned)(unsigned short)f2bf(acc1 * inv) << 16) |
            (unsigned)(unsigned short)f2bf(acc0 * inv);
}

// ---------------------------------------------------------------------------
extern "C" void kernel_launch(void* const* d_in, const int* in_sizes, int n_in,
                              void* d_out, int out_size, void* d_ws, size_t ws_size,
                              hipStream_t stream)
{
    const float* node_states = (const float*)d_in[0];
    const int*   edges       = (const int*)d_in[1];
    const float* w_qkv = (const float*)d_in[2];
    const float* b_qkv = (const float*)d_in[3];
    const float* w_out = (const float*)d_in[4];
    const float* b_out = (const float*)d_in[5];
    const float* w1    = (const float*)d_in[6];
    const float* b1    = (const float*)d_in[7];
    const float* w2    = (const float*)d_in[8];
    const float* b2    = (const float*)d_in[9];
    const float* g1    = (const float*)d_in[10];
    const float* beta1 = (const float*)d_in[11];
    const float* g2    = (const float*)d_in[12];
    const float* beta2 = (const float*)d_in[13];

    const int N  = in_sizes[0] / D_DIM;      // 40000
    const int M  = in_sizes[1] / 2;          // 640000
    const int MP = ((N + 127) / 128) * 128;  // 40064
    const int* e_src = edges;
    const int* e_tgt = edges + M;

    float* out_new = (float*)d_out;
    float* out_old = (float*)d_out + (size_t)N * D_DIM;

    size_t off = 0;
    auto alloc = [&](size_t bytes) -> void* {
        void* p = (char*)d_ws + off;
        off += (bytes + 255) & ~(size_t)255;
        return p;
    };
    short* ns_bf   = (short*)alloc((size_t)MP * D_DIM * 2);
    // region: qkv_bf [MP][384] early; xbuf f32 + xbuf_bf later (qkv dead)
    char*  region  = (char*)alloc((size_t)MP * 384 * 2);
    short* qkv_bf  = (short*)region;
    float* xbuf    = (float*)region;
    short* xbuf_bf = (short*)(region + (size_t)MP * D_DIM * 4);
    short* agg_bf  = (short*)alloc((size_t)MP * D_DIM * 2);
    short* ff1_bf  = (short*)alloc((size_t)MP * FF_DIM * 2);
    short* wqkv_bf = (short*)alloc((size_t)384 * 128 * 2);
    short* wout_bf = (short*)alloc((size_t)128 * 128 * 2);
    short* w1_bf   = (short*)alloc((size_t)512 * 128 * 2);
    short* w2_bf   = (short*)alloc((size_t)128 * 512 * 2);
    int* counts    = (int*)alloc((size_t)(N + 1) * 4);   // [N] = global cursor
    int* offsets   = (int*)alloc((size_t)N * 4);
    int* cursor    = (int*)alloc((size_t)N * 4);
    int* csr_src   = (int*)alloc((size_t)M * 4);
    (void)ws_size;

    // 1) prep: conversions + old copy + zero counts/gcur
    prep_kernel<<<(MP * D_DIM / 4 + 255) / 256, 256, 0, stream>>>(
        node_states, ns_bf, out_old, N * D_DIM, MP * D_DIM,
        w_qkv, w_out, w1, w2, wqkv_bf, wout_bf, w1_bf, w2_bf,
        384 * 128, 128 * 128, 512 * 128, 128 * 512,
        counts, N + 1);

    // 2) CSR build
    count_kernel<<<(M + 255) / 256, 256, 0, stream>>>(e_tgt, counts, M);
    alloc_kernel<<<(N + 255) / 256, 256, 0, stream>>>(counts, offsets, cursor, N);
    scatter_kernel<<<(M + 255) / 256, 256, 0, stream>>>(e_src, e_tgt, cursor,
                                                        csr_src, M);

    // 3) qkv = ns @ w_qkv^T + b_qkv  (bf16 out, KV-interleaved)
    {
        dim3 grid(384 / 128, MP / 128);
        gemm_mfma<1, 0, 1><<<grid, 256, 0, stream>>>(ns_bf, wqkv_bf, b_qkv,
                                                     qkv_bf, 384, 128);
    }
    // 4) attention aggregation
    attn_kernel<<<MP / 4, 256, 0, stream>>>(qkv_bf, offsets, counts, csr_src,
                                            agg_bf, N, MP);
    // 5) x = LN(ns + agg @ w_out^T + b_out)  -> xbuf f32 + xbuf_bf (fused)
    gemm_ln<128, 1><<<MP / 128, 256, 0, stream>>>(
        agg_bf, wout_bf, b_out, node_states, g1, beta1, xbuf, xbuf_bf, N);
    // 6) ff1 = relu(x @ w1^T + b1)  (bf16 out)
    {
        dim3 grid(FF_DIM / 128, MP / 128);
        gemm_mfma<1, 1, 0><<<grid, 256, 0, stream>>>(xbuf_bf, w1_bf, b1,
                                                     ff1_bf, FF_DIM, 128);
    }
    // 7) out = LN(x + ff1 @ w2^T + b2)  (fused)
    gemm_ln<512, 0><<<MP / 128, 256, 0, stream>>>(
        ff1_bf, w2_bf, b2, xbuf, g2, beta2, out_new, (short*)nullptr, N);
}

// Round 6
// 217.392 us; speedup vs baseline: 1.0233x; 1.0233x over previous
//
#include <hip/hip_runtime.h>
#include <hip/hip_bf16.h>
#include <math.h>

#define D_DIM 128
#define FF_DIM 512

typedef __attribute__((ext_vector_type(8))) short bf16x8;
typedef __attribute__((ext_vector_type(4))) float f32x4;
typedef __attribute__((ext_vector_type(4))) unsigned short u16x4;

__device__ __forceinline__ short f2bf(float f) {
    union { float f; unsigned u; } x; x.f = f;
    unsigned r = x.u + 0x7FFF + ((x.u >> 16) & 1);
    return (short)(r >> 16);
}
__device__ __forceinline__ float bf2f(short s) {
    union { unsigned u; float f; } x;
    x.u = ((unsigned)(unsigned short)s) << 16;
    return x.f;
}
// bf16 pair unpack: low short -> f32, high short -> f32 (1 VALU op each)
__device__ __forceinline__ float lof(unsigned u) {
    union { unsigned u; float f; } x; x.u = u << 16; return x.f;
}
__device__ __forceinline__ float hif(unsigned u) {
    union { unsigned u; float f; } x; x.u = u & 0xFFFF0000u; return x.f;
}

__device__ __forceinline__ void load_lds16(const short* g, short* l) {
    __builtin_amdgcn_global_load_lds(
        (const __attribute__((address_space(1))) unsigned int*)g,
        (__attribute__((address_space(3))) unsigned int*)l, 16, 0, 0);
}

// ---------------------------------------------------------------------------
// bf16 MFMA GEMM: C[MP,Nc] = A[MP,K] @ W[Nc,K]^T + bias (+relu) (f32/bf16 C)
// 128x128 tile, BK=32, 256 threads (4 waves, 2x2), 4x4 16x16 frags per wave.
// ---------------------------------------------------------------------------
template<int OUT_BF16, int RELU>
__global__ __launch_bounds__(256) void gemm_mfma(
    const short* __restrict__ A, const short* __restrict__ B,
    const float* __restrict__ bias, void* __restrict__ C,
    int Nc, int K)
{
    __shared__ short lA[128 * 32];
    __shared__ short lB[128 * 32];

    const int tid  = threadIdx.x;
    const int lane = tid & 63;
    const int wave = tid >> 6;
    const int wr = wave >> 1, wc = wave & 1;
    const int row0 = blockIdx.y * 128;
    const int col0 = blockIdx.x * 128;
    const int fr = lane & 15;
    const int fq = lane >> 4;
    const int sw = (fr >> 1) & 3;
    const int rdoff = (fq ^ sw) * 8;

    f32x4 acc[4][4] = {};

    for (int k0 = 0; k0 < K; k0 += 32) {
        __syncthreads();
#pragma unroll
        for (int i = 0; i < 2; ++i) {
            int c  = i * 256 + tid;
            int r  = c >> 2;
            int qs = c & 3;
            int qg = qs ^ ((r >> 1) & 3);
            load_lds16(A + (size_t)(row0 + r) * K + k0 + qg * 8, lA + c * 8);
            load_lds16(B + (size_t)(col0 + r) * K + k0 + qg * 8, lB + c * 8);
        }
        __syncthreads();

        bf16x8 af[4], bfr[4];
#pragma unroll
        for (int m = 0; m < 4; ++m)
            af[m] = *(const bf16x8*)&lA[(wr * 64 + m * 16 + fr) * 32 + rdoff];
#pragma unroll
        for (int n2 = 0; n2 < 4; ++n2)
            bfr[n2] = *(const bf16x8*)&lB[(wc * 64 + n2 * 16 + fr) * 32 + rdoff];
#pragma unroll
        for (int m = 0; m < 4; ++m)
#pragma unroll
            for (int n2 = 0; n2 < 4; ++n2)
                acc[m][n2] = __builtin_amdgcn_mfma_f32_16x16x32_bf16(
                    af[m], bfr[n2], acc[m][n2], 0, 0, 0);
    }

#pragma unroll
    for (int m = 0; m < 4; ++m) {
        int r = row0 + wr * 64 + m * 16 + fq * 4;
#pragma unroll
        for (int n2 = 0; n2 < 4; ++n2) {
            int c = col0 + wc * 64 + n2 * 16 + fr;
            float bb = bias[c];
#pragma unroll
            for (int j = 0; j < 4; ++j) {
                float v = acc[m][n2][j] + bb;
                if (RELU) v = fmaxf(v, 0.0f);
                if (OUT_BF16)
                    ((short*)C)[(size_t)(r + j) * Nc + c] = f2bf(v);
                else
                    ((float*)C)[(size_t)(r + j) * Nc + c] = v;
            }
        }
    }
}

// ---------------------------------------------------------------------------
// Fused GEMM (Nc=128, 128x128 tile) + residual + LayerNorm epilogue.
// RES_BF: residual is bf16 (else f32). OUT_BF: write bf16 (pad rows zeroed),
// else write f32 rows<n only.
// ---------------------------------------------------------------------------
template<int KD, int RES_BF, int OUT_BF>
__global__ __launch_bounds__(256) void gemm_ln(
    const short* __restrict__ A, const short* __restrict__ B,
    const float* __restrict__ bias, const void* __restrict__ res,
    const float* __restrict__ gamma, const float* __restrict__ beta,
    float* __restrict__ out32, short* __restrict__ outbf, int n)
{
    __shared__ short lA[128 * 32];
    __shared__ short lB[128 * 32];
    __shared__ float sums[128][2], sqs[128][2];
    __shared__ float muA[128], rsA[128];

    const int tid  = threadIdx.x;
    const int lane = tid & 63;
    const int wave = tid >> 6;
    const int wr = wave >> 1, wc = wave & 1;
    const int row0 = blockIdx.x * 128;
    const int fr = lane & 15;
    const int fq = lane >> 4;
    const int sw = (fr >> 1) & 3;
    const int rdoff = (fq ^ sw) * 8;

    f32x4 acc[4][4] = {};

    for (int k0 = 0; k0 < KD; k0 += 32) {
        __syncthreads();
#pragma unroll
        for (int i = 0; i < 2; ++i) {
            int c  = i * 256 + tid;
            int r  = c >> 2;
            int qs = c & 3;
            int qg = qs ^ ((r >> 1) & 3);
            load_lds16(A + (size_t)(row0 + r) * KD + k0 + qg * 8, lA + c * 8);
            load_lds16(B + (size_t)r * KD + k0 + qg * 8, lB + c * 8);
        }
        __syncthreads();

        bf16x8 af[4], bfr[4];
#pragma unroll
        for (int m = 0; m < 4; ++m)
            af[m] = *(const bf16x8*)&lA[(wr * 64 + m * 16 + fr) * 32 + rdoff];
#pragma unroll
        for (int n2 = 0; n2 < 4; ++n2)
            bfr[n2] = *(const bf16x8*)&lB[(wc * 64 + n2 * 16 + fr) * 32 + rdoff];
#pragma unroll
        for (int m = 0; m < 4; ++m)
#pragma unroll
            for (int n2 = 0; n2 < 4; ++n2)
                acc[m][n2] = __builtin_amdgcn_mfma_f32_16x16x32_bf16(
                    af[m], bfr[n2], acc[m][n2], 0, 0, 0);
    }

    float bicol[4], gcol[4], bcol[4];
#pragma unroll
    for (int n2 = 0; n2 < 4; ++n2) {
        int c = wc * 64 + n2 * 16 + fr;
        bicol[n2] = bias[c]; gcol[n2] = gamma[c]; bcol[n2] = beta[c];
    }

#pragma unroll
    for (int m = 0; m < 4; ++m) {
#pragma unroll
        for (int j = 0; j < 4; ++j) {
            int rl = wr * 64 + m * 16 + fq * 4 + j;
            int rg = row0 + rl;
            float ps = 0.0f, pq = 0.0f;
#pragma unroll
            for (int n2 = 0; n2 < 4; ++n2) {
                float v = acc[m][n2][j] + bicol[n2];
                if (rg < n) {
                    size_t ri = (size_t)rg * 128 + wc * 64 + n2 * 16 + fr;
                    v += RES_BF ? bf2f(((const short*)res)[ri])
                                : ((const float*)res)[ri];
                }
                acc[m][n2][j] = v;
                ps += v; pq += v * v;
            }
            ps += __shfl_xor(ps, 1); ps += __shfl_xor(ps, 2);
            ps += __shfl_xor(ps, 4); ps += __shfl_xor(ps, 8);
            pq += __shfl_xor(pq, 1); pq += __shfl_xor(pq, 2);
            pq += __shfl_xor(pq, 4); pq += __shfl_xor(pq, 8);
            if (fr == 0) { sums[rl][wc] = ps; sqs[rl][wc] = pq; }
        }
    }
    __syncthreads();
    if (tid < 128) {
        float s = sums[tid][0] + sums[tid][1];
        float q = sqs[tid][0] + sqs[tid][1];
        float mu = s * (1.0f / 128.0f);
        float var = q * (1.0f / 128.0f) - mu * mu;
        muA[tid] = mu;
        rsA[tid] = rsqrtf(var + 1e-5f);
    }
    __syncthreads();

#pragma unroll
    for (int m = 0; m < 4; ++m) {
#pragma unroll
        for (int j = 0; j < 4; ++j) {
            int rl = wr * 64 + m * 16 + fq * 4 + j;
            int rg = row0 + rl;
            float mu = muA[rl], rs = rsA[rl];
#pragma unroll
            for (int n2 = 0; n2 < 4; ++n2) {
                int c = wc * 64 + n2 * 16 + fr;
                float o = gcol[n2] * (acc[m][n2][j] - mu) * rs + bcol[n2];
                if (OUT_BF) {
                    outbf[(size_t)rg * 128 + c] = (rg < n) ? f2bf(o) : (short)0;
                } else {
                    if (rg < n) out32[(size_t)rg * 128 + c] = o;
                }
            }
        }
    }
}

// ---------------------------------------------------------------------------
// prep: ns f32->bf16 (+ old copy, pad zero), weights ->bf16, zero counts/gcur
// ---------------------------------------------------------------------------
__global__ __launch_bounds__(256) void prep_kernel(
    const float* __restrict__ ns, short* __restrict__ nsbf,
    float* __restrict__ out_old, int n_elems, int mp_elems,
    const float* w0, const float* w1, const float* w2, const float* w3,
    short* o0, short* o1, short* o2, short* o3,
    int c0, int c1, int c2, int c3,
    int* __restrict__ counts, int nc1)
{
    int i = blockIdx.x * 256 + threadIdx.x;
    int i4 = i * 4;
    if (i4 < mp_elems) {
        if (i4 < n_elems) {
            float4 v = *(const float4*)(ns + i4);
            *(float4*)(out_old + i4) = v;
            u16x4 b;
            b.x = (unsigned short)f2bf(v.x); b.y = (unsigned short)f2bf(v.y);
            b.z = (unsigned short)f2bf(v.z); b.w = (unsigned short)f2bf(v.w);
            *(u16x4*)(nsbf + i4) = b;
        } else {
            u16x4 z = {0, 0, 0, 0};
            *(u16x4*)(nsbf + i4) = z;
        }
    }
    if (i < c0) o0[i] = f2bf(w0[i]);
    if (i < c1) o1[i] = f2bf(w1[i]);
    if (i < c2) o2[i] = f2bf(w2[i]);
    if (i < c3) o3[i] = f2bf(w3[i]);
    if (i < nc1) counts[i] = 0;
}

// ---------------------------------------------------------------------------
// CSR build: count -> atomic base alloc -> scatter (bucket order arbitrary)
// ---------------------------------------------------------------------------
__global__ __launch_bounds__(256) void count_kernel(
    const int* __restrict__ tgt, int* __restrict__ counts, int m)
{
    int i = blockIdx.x * blockDim.x + threadIdx.x;
    if (i < m) atomicAdd(&counts[tgt[i]], 1);
}

__global__ __launch_bounds__(256) void alloc_kernel(
    int* __restrict__ counts, int* __restrict__ offs,
    int* __restrict__ cursor, int n)
{
    int i = blockIdx.x * 256 + threadIdx.x;
    if (i < n) {
        int c = counts[i];
        int base = atomicAdd(&counts[n], c);
        offs[i] = base;
        cursor[i] = base;
    }
}

__global__ __launch_bounds__(256) void scatter_kernel(
    const int* __restrict__ src, const int* __restrict__ tgt,
    int* __restrict__ cursor, int* __restrict__ csr_src, int m)
{
    int i = blockIdx.x * blockDim.x + threadIdx.x;
    if (i < m) {
        int pos = atomicAdd(&cursor[tgt[i]], 1);
        csr_src[pos] = src[i];
    }
}

// ---------------------------------------------------------------------------
// Per-target-node attention, half-head lane layout:
//   lane = hh*4 + e: hh in 0..15 owns dims [hh*8, hh*8+8); e = edge slot 0..3.
// Score: lane-local 8-dim dot + 1 shfl_xor(4) (head = hh pair).
// 4 edges per pass, 2-deep prefetch, online softmax with exp2.
// qkv layout: [MP][384] bf16, plain q|k|v.
// ---------------------------------------------------------------------------
__global__ __launch_bounds__(256) void attn_kernel(
    const short* __restrict__ qkv, const int* __restrict__ offsets,
    const int* __restrict__ counts, const int* __restrict__ csr_src,
    short* __restrict__ agg, int n, int mp)
{
    int node = blockIdx.x * 4 + (threadIdx.x >> 6);
    int lane = threadIdx.x & 63;
    if (node >= mp) return;
    const int hh = lane >> 2;
    const int e  = lane & 3;
    unsigned* outp = (unsigned*)(agg + (size_t)node * 128 + hh * 8 + e * 2);

    int beg = 0, cnt = 0;
    if (node < n) { beg = offsets[node]; cnt = counts[node]; }
    if (cnt == 0) { *outp = 0u; return; }

    // q dims [hh*8 .. +8) -> f32 (once per node)
    const uint4 qd = *(const uint4*)(qkv + (size_t)node * 384 + hh * 8);
    float qf0 = lof(qd.x), qf1 = hif(qd.x), qf2 = lof(qd.y), qf3 = hif(qd.y);
    float qf4 = lof(qd.z), qf5 = hif(qd.z), qf6 = lof(qd.w), qf7 = hif(qd.w);

    const float SC = 0.25f * 1.44269504088896340736f;  // scale * log2(e)
    float m = -INFINITY, l = 0.0f;
    float a0 = 0, a1 = 0, a2 = 0, a3 = 0, a4 = 0, a5 = 0, a6 = 0, a7 = 0;

    const short* kbase = qkv + 128 + hh * 8;
    const short* vbase = qkv + 256 + hh * 8;

    int sA = csr_src[beg + ((e < cnt) ? e : 0)];
    uint4 kA = *(const uint4*)(kbase + (size_t)sA * 384);
    uint4 vA = *(const uint4*)(vbase + (size_t)sA * 384);

    for (int g = 0; g < cnt; g += 4) {
        uint4 kB = kA, vB = vA;
        if (g + 4 < cnt) {
            int t = g + 4 + e;
            int sB = csr_src[beg + ((t < cnt) ? t : 0)];
            kB = *(const uint4*)(kbase + (size_t)sB * 384);
            vB = *(const uint4*)(vbase + (size_t)sB * 384);
        }
        // lane-local 8-dim dot
        float s;
        s = qf0 * lof(kA.x);
        s = fmaf(qf1, hif(kA.x), s);
        s = fmaf(qf2, lof(kA.y), s);
        s = fmaf(qf3, hif(kA.y), s);
        s = fmaf(qf4, lof(kA.z), s);
        s = fmaf(qf5, hif(kA.z), s);
        s = fmaf(qf6, lof(kA.w), s);
        s = fmaf(qf7, hif(kA.w), s);
        s += __shfl_xor(s, 4);                       // combine hh pair -> head
        float sc = (g + e < cnt) ? s * SC : -INFINITY;
        float gm = fmaxf(sc, __shfl_xor(sc, 1));     // max over 4 edge slots
        gm = fmaxf(gm, __shfl_xor(gm, 2));
        float mnew = fmaxf(m, gm);
        float corr = exp2f(m - mnew);
        float p = exp2f(sc - mnew);
        l = fmaf(l, corr, p);
        a0 = fmaf(a0, corr, p * lof(vA.x));
        a1 = fmaf(a1, corr, p * hif(vA.x));
        a2 = fmaf(a2, corr, p * lof(vA.y));
        a3 = fmaf(a3, corr, p * hif(vA.y));
        a4 = fmaf(a4, corr, p * lof(vA.z));
        a5 = fmaf(a5, corr, p * hif(vA.z));
        a6 = fmaf(a6, corr, p * lof(vA.w));
        a7 = fmaf(a7, corr, p * hif(vA.w));
        m = mnew;
        kA = kB; vA = vB;
    }

    // reduce over the 4 edge slots (lane bits 0-1)
    l  += __shfl_xor(l, 1);
    a0 += __shfl_xor(a0, 1); a1 += __shfl_xor(a1, 1);
    a2 += __shfl_xor(a2, 1); a3 += __shfl_xor(a3, 1);
    a4 += __shfl_xor(a4, 1); a5 += __shfl_xor(a5, 1);
    a6 += __shfl_xor(a6, 1); a7 += __shfl_xor(a7, 1);
    l  += __shfl_xor(l, 2);
    a0 += __shfl_xor(a0, 2); a1 += __shfl_xor(a1, 2);
    a2 += __shfl_xor(a2, 2); a3 += __shfl_xor(a3, 2);
    a4 += __shfl_xor(a4, 2); a5 += __shfl_xor(a5, 2);
    a6 += __shfl_xor(a6, 2); a7 += __shfl_xor(a7, 2);

    float inv = 1.0f / l;   // l >= 1 when cnt > 0
    float o0, o1;
    if (e == 0)      { o0 = a0; o1 = a1; }
    else if (e == 1) { o0 = a2; o1 = a3; }
    else if (e == 2) { o0 = a4; o1 = a5; }
    else             { o0 = a6; o1 = a7; }
    *outp = ((unsigned)(unsigned short)f2bf(o1 * inv) << 16) |
            (unsigned)(unsigned short)f2bf(o0 * inv);
}

// ---------------------------------------------------------------------------
extern "C" void kernel_launch(void* const* d_in, const int* in_sizes, int n_in,
                              void* d_out, int out_size, void* d_ws, size_t ws_size,
                              hipStream_t stream)
{
    const float* node_states = (const float*)d_in[0];
    const int*   edges       = (const int*)d_in[1];
    const float* w_qkv = (const float*)d_in[2];
    const float* b_qkv = (const float*)d_in[3];
    const float* w_out = (const float*)d_in[4];
    const float* b_out = (const float*)d_in[5];
    const float* w1    = (const float*)d_in[6];
    const float* b1    = (const float*)d_in[7];
    const float* w2    = (const float*)d_in[8];
    const float* b2    = (const float*)d_in[9];
    const float* g1    = (const float*)d_in[10];
    const float* beta1 = (const float*)d_in[11];
    const float* g2    = (const float*)d_in[12];
    const float* beta2 = (const float*)d_in[13];

    const int N  = in_sizes[0] / D_DIM;      // 40000
    const int M  = in_sizes[1] / 2;          // 640000
    const int MP = ((N + 127) / 128) * 128;  // 40064
    const int* e_src = edges;
    const int* e_tgt = edges + M;

    float* out_new = (float*)d_out;
    float* out_old = (float*)d_out + (size_t)N * D_DIM;

    size_t off = 0;
    auto alloc = [&](size_t bytes) -> void* {
        void* p = (char*)d_ws + off;
        off += (bytes + 255) & ~(size_t)255;
        return p;
    };
    short* ns_bf   = (short*)alloc((size_t)MP * D_DIM * 2);
    // region: qkv_bf [MP][384] early; xbuf_bf [MP][128] later (qkv dead then)
    char*  region  = (char*)alloc((size_t)MP * 384 * 2);
    short* qkv_bf  = (short*)region;
    short* xbuf_bf = (short*)region;
    short* agg_bf  = (short*)alloc((size_t)MP * D_DIM * 2);
    short* ff1_bf  = (short*)alloc((size_t)MP * FF_DIM * 2);
    short* wqkv_bf = (short*)alloc((size_t)384 * 128 * 2);
    short* wout_bf = (short*)alloc((size_t)128 * 128 * 2);
    short* w1_bf   = (short*)alloc((size_t)512 * 128 * 2);
    short* w2_bf   = (short*)alloc((size_t)128 * 512 * 2);
    int* counts    = (int*)alloc((size_t)(N + 1) * 4);   // [N] = global cursor
    int* offsets   = (int*)alloc((size_t)N * 4);
    int* cursor    = (int*)alloc((size_t)N * 4);
    int* csr_src   = (int*)alloc((size_t)M * 4);
    (void)ws_size;

    // 1) prep: conversions + old copy + zero counts/cursor
    prep_kernel<<<(MP * D_DIM / 4 + 255) / 256, 256, 0, stream>>>(
        node_states, ns_bf, out_old, N * D_DIM, MP * D_DIM,
        w_qkv, w_out, w1, w2, wqkv_bf, wout_bf, w1_bf, w2_bf,
        384 * 128, 128 * 128, 512 * 128, 128 * 512,
        counts, N + 1);

    // 2) CSR build
    count_kernel<<<(M + 255) / 256, 256, 0, stream>>>(e_tgt, counts, M);
    alloc_kernel<<<(N + 255) / 256, 256, 0, stream>>>(counts, offsets, cursor, N);
    scatter_kernel<<<(M + 255) / 256, 256, 0, stream>>>(e_src, e_tgt, cursor,
                                                        csr_src, M);

    // 3) qkv = ns @ w_qkv^T + b_qkv  (bf16 out, plain q|k|v)
    {
        dim3 grid(384 / 128, MP / 128);
        gemm_mfma<1, 0><<<grid, 256, 0, stream>>>(ns_bf, wqkv_bf, b_qkv,
                                                  qkv_bf, 384, 128);
    }
    // 4) attention aggregation
    attn_kernel<<<MP / 4, 256, 0, stream>>>(qkv_bf, offsets, counts, csr_src,
                                            agg_bf, N, MP);
    // 5) x = LN(ns + agg @ w_out^T + b_out)  -> xbuf_bf (bf16 only)
    gemm_ln<128, 0, 1><<<MP / 128, 256, 0, stream>>>(
        agg_bf, wout_bf, b_out, node_states, g1, beta1,
        (float*)nullptr, xbuf_bf, N);
    // 6) ff1 = relu(x @ w1^T + b1)  (bf16 out)
    {
        dim3 grid(FF_DIM / 128, MP / 128);
        gemm_mfma<1, 1><<<grid, 256, 0, stream>>>(xbuf_bf, w1_bf, b1,
                                                  ff1_bf, FF_DIM, 128);
    }
    // 7) out = LN(x + ff1 @ w2^T + b2)  (bf16 residual, f32 out)
    gemm_ln<512, 1, 0><<<MP / 128, 256, 0, stream>>>(
        ff1_bf, w2_bf, b2, xbuf_bf, g2, beta2, out_new, (short*)nullptr, N);
}